// Round 8
// baseline (904.924 us; speedup 1.0000x reference)
//
#include <hip/hip_runtime.h>
#include <cmath>

#define BATCH 2
#define LSEQ 2048
#define DMODEL 1024
#define DINNER 2048
#define NHEADS 32
#define DHEAD 64
#define DSTATE 64
#define DCONV 4
#define CONVDIM (DINNER + 2*DSTATE)            // 2176
#define DINPROJ (2*DINNER + 2*DSTATE + NHEADS) // 4256
#define DINPROJ_PAD 4352                       // 34*128
#define CHUNKSZ 256
#define NCHUNK (LSEQ/CHUNKSZ)                  // 8
#define MROWS (BATCH*LSEQ)                     // 4096
#define EPSF 1e-5f

typedef __attribute__((ext_vector_type(8))) short shortx8;
typedef __attribute__((ext_vector_type(4))) short shortx4;
typedef __attribute__((ext_vector_type(4))) float floatx4;

__device__ __forceinline__ ushort f2bf(float f) {
  unsigned u = __float_as_uint(f);
  unsigned r = (u + 0x7fffu + ((u >> 16) & 1u)) >> 16;
  return (ushort)r;
}
__device__ __forceinline__ float bf2f(ushort b) {
  return __uint_as_float(((unsigned)b) << 16);
}

__device__ __forceinline__ shortx8 pack8(float4 a, float4 b) {
  shortx8 r;
  r[0] = (short)f2bf(a.x); r[1] = (short)f2bf(a.y);
  r[2] = (short)f2bf(a.z); r[3] = (short)f2bf(a.w);
  r[4] = (short)f2bf(b.x); r[5] = (short)f2bf(b.y);
  r[6] = (short)f2bf(b.z); r[7] = (short)f2bf(b.w);
  return r;
}

__device__ __forceinline__ void async_load16(const void* g, void* l) {
  __builtin_amdgcn_global_load_lds(
      (const __attribute__((address_space(1))) void*)g,
      (__attribute__((address_space(3))) void*)l, 16, 0, 0);
}

// ---------------- reductions ----------------
__device__ __forceinline__ float block_reduce_sum_256(float v, float* sb) {
  for (int off = 32; off > 0; off >>= 1) v += __shfl_down(v, off, 64);
  int lane = threadIdx.x & 63, wid = threadIdx.x >> 6;
  if (lane == 0) sb[wid] = v;
  __syncthreads();
  return sb[0] + sb[1] + sb[2] + sb[3];
}

// ---------------- fp32 -> bf16 (with zero tail padding), per-layer fallback ----------------
__global__ __launch_bounds__(256) void cvt_bf16_k(const float* __restrict__ src,
                                                  ushort* __restrict__ dst,
                                                  size_t n_src, size_t n_dst) {
  size_t i = (size_t)blockIdx.x * 256 + threadIdx.x;
  if (i >= n_dst) return;
  float v = (i < n_src) ? src[i] : 0.f;
  dst[i] = f2bf(v);
}

// ---------------- ALL-layer weight cvt (hoisted, vectorized 8 elem/thread) ----------------
__global__ __launch_bounds__(256) void cvt_w_all(const float* __restrict__ in_w,
                                                 const float* __restrict__ out_w,
                                                 ushort* __restrict__ in_bf,
                                                 ushort* __restrict__ out_bf) {
  unsigned g = (blockIdx.x * 256u + threadIdx.x) * 8u;
  const unsigned PL = (unsigned)DINPROJ_PAD * DMODEL;         // 4,456,448
  const unsigned n1 = 4u * PL;                                 // 17,825,792
  const unsigned n2 = 4u * DMODEL * DINNER;                    // 8,388,608
  if (g < n1) {
    unsigned layer = g / PL, rem = g % PL;
    unsigned row = rem / DMODEL, col = rem % DMODEL;  // col 8-aligned, in-row
    shortx8 o;
    if (row < DINPROJ) {
      const float* sp = in_w + ((size_t)layer * DINPROJ + row) * DMODEL + col;
      float4 a = *(const float4*)sp;
      float4 b = *(const float4*)(sp + 4);
      o = pack8(a, b);
    } else {
#pragma unroll
      for (int j = 0; j < 8; j++) o[j] = 0;
    }
    *(shortx8*)(in_bf + g) = o;
  } else if (g < n1 + n2) {
    unsigned j = g - n1;
    const float* sp = out_w + j;
    float4 a = *(const float4*)sp;
    float4 b = *(const float4*)(sp + 4);
    *(shortx8*)(out_bf + j) = pack8(a, b);
  }
}

// ---------------- rmsnorm (width 1024) -> bf16 out (vectorized) ----------------
__global__ __launch_bounds__(256) void rmsnorm_k(const float* __restrict__ x,
                                                 const float* __restrict__ w,
                                                 ushort* __restrict__ out) {
  __shared__ float sb[4];
  int r = blockIdx.x;
  const float* xr = x + (size_t)r * DMODEL;
  ushort* orow = out + (size_t)r * DMODEL;
  int c0 = threadIdx.x * 4;
  float4 v4 = *(const float4*)(xr + c0);
  float ssq = v4.x * v4.x + v4.y * v4.y + v4.z * v4.z + v4.w * v4.w;
  float s = block_reduce_sum_256(ssq, sb);
  float sc = rsqrtf(s / (float)DMODEL + EPSF);
  float4 w4 = *(const float4*)(w + c0);
  shortx4 o;
  o[0] = (short)f2bf(v4.x * sc * w4.x);
  o[1] = (short)f2bf(v4.y * sc * w4.y);
  o[2] = (short)f2bf(v4.z * sc * w4.z);
  o[3] = (short)f2bf(v4.w * sc * w4.w);
  *(shortx4*)(orow + c0) = o;
}

// ---------------- pipelined MFMA bf16 NT GEMM, 128x128 tile (GEMM1) ----------------
__device__ __forceinline__ void stage_tile(const ushort* __restrict__ A,
                                           const ushort* __restrict__ B,
                                           char* lb, int m0, int n0, int K, int k0,
                                           int wid, int rA, int sA) {
#pragma unroll
  for (int rd = 0; rd < 2; rd++) {
    int r = rd * 64 + rA;
    int sl = sA ^ ((r ^ (r >> 2)) & 3);
    async_load16(A + (size_t)(m0 + r) * K + (k0 + sl * 8), lb + rd * 4096 + wid * 1024);
  }
#pragma unroll
  for (int rd = 0; rd < 2; rd++) {
    int r = rd * 64 + rA;
    int sl = sA ^ ((r ^ (r >> 2)) & 3);
    async_load16(B + (size_t)(n0 + r) * K + (k0 + sl * 8), lb + 8192 + rd * 4096 + wid * 1024);
  }
}

__global__ __launch_bounds__(256, 3) void gemm_nt_mfma_pipe(
    const ushort* __restrict__ A, const ushort* __restrict__ B,
    ushort* __restrict__ Cbf, int M, int N, int K,
    int nbx, int rw, int rh) {
  __shared__ __align__(16) char lds[3][16384];
  int tid = threadIdx.x;
  int wid = tid >> 6, lane = tid & 63;
  int quad = lane >> 4, lrow = lane & 15;

  int d = blockIdx.x;
  int xcd = d & 7, wi = d >> 3;
  int ra = nbx / rw;
  int rn = xcd % ra, rm = xcd / ra;
  int bx = rn * rw + wi % rw;
  int by = rm * rh + wi / rw;

  int m0 = by * 128, n0 = bx * 128;
  int wm = (wid >> 1) * 64, wn = (wid & 1) * 64;
  int rA = tid >> 2, sA = tid & 3;

  floatx4 acc[4][4];
#pragma unroll
  for (int i = 0; i < 4; i++)
#pragma unroll
    for (int j = 0; j < 4; j++) acc[i][j] = (floatx4){0.f, 0.f, 0.f, 0.f};

  int NT = K >> 5;
#pragma unroll
  for (int t = 0; t < 2; t++)
    stage_tile(A, B, lds[t], m0, n0, K, t * 32, wid, rA, sA);

  int cur = 0, sb = 2;
  for (int t = 0; t < NT; t++) {
    if (t < NT - 1) asm volatile("s_waitcnt vmcnt(4)" ::: "memory");
    else            asm volatile("s_waitcnt vmcnt(0)" ::: "memory");
    __builtin_amdgcn_s_barrier();
    __builtin_amdgcn_sched_barrier(0);
    if (t + 2 < NT) {
      stage_tile(A, B, lds[sb], m0, n0, K, (t + 2) * 32, wid, rA, sA);
      sb = (sb == 2) ? 0 : sb + 1;
    }

    const char* Ab = lds[cur];
    const char* Bb = Ab + 8192;
    cur = (cur == 2) ? 0 : cur + 1;
    shortx8 af[4], bfr[4];
#pragma unroll
    for (int i = 0; i < 4; i++) {
      int r = wm + i * 16 + lrow;
      af[i] = *(const shortx8*)(Ab + r * 64 + ((quad ^ ((r ^ (r >> 2)) & 3)) << 4));
    }
#pragma unroll
    for (int j = 0; j < 4; j++) {
      int r = wn + j * 16 + lrow;
      bfr[j] = *(const shortx8*)(Bb + r * 64 + ((quad ^ ((r ^ (r >> 2)) & 3)) << 4));
    }
    __builtin_amdgcn_s_setprio(1);
#pragma unroll
    for (int i = 0; i < 4; i++)
#pragma unroll
      for (int j = 0; j < 4; j++)
        acc[i][j] = __builtin_amdgcn_mfma_f32_16x16x32_bf16(af[i], bfr[j], acc[i][j], 0, 0, 0);
    __builtin_amdgcn_s_setprio(0);
  }

#pragma unroll
  for (int i = 0; i < 4; i++) {
    int r0 = m0 + wm + i * 16 + quad * 4;
#pragma unroll
    for (int j = 0; j < 4; j++) {
      int n = n0 + wn + j * 16 + lrow;
      if (n < N)
#pragma unroll
        for (int r = 0; r < 4; r++)
          Cbf[(size_t)(r0 + r) * N + n] = f2bf(acc[i][j][r]);
    }
  }
}

// ---------------- pipelined MFMA bf16 NT GEMM, 64x64 tile (GEMM2) ----------------
// Grid 1024 blocks = 4 blocks/CU = 16 waves/CU (R7 validated: TLP is the lever
// for this latency-bound structure). 3 LDS buffers x 8 KB; 2 loads/thread/stage
// -> steady vmcnt(2); depth-2 post-barrier stage placement (CFG0 schedule).
__device__ __forceinline__ void stage_tile64(const ushort* __restrict__ A,
                                             const ushort* __restrict__ B,
                                             char* lb, int m0, int n0, int K, int k0,
                                             int wid, int rA, int sA) {
  int sl = sA ^ ((rA ^ (rA >> 2)) & 3);
  async_load16(A + (size_t)(m0 + rA) * K + (k0 + sl * 8), lb + wid * 1024);
  async_load16(B + (size_t)(n0 + rA) * K + (k0 + sl * 8), lb + 4096 + wid * 1024);
}

__global__ __launch_bounds__(256, 4) void gemm_nt_64(
    const ushort* __restrict__ A, const ushort* __restrict__ B,
    float* __restrict__ C, const float* __restrict__ resid,
    int M, int N, int K, int nbx, int rw, int rh) {
  __shared__ __align__(16) char lds[3][8192];
  int tid = threadIdx.x;
  int wid = tid >> 6, lane = tid & 63;
  int quad = lane >> 4, lrow = lane & 15;

  int d = blockIdx.x;
  int xcd = d & 7, wi = d >> 3;
  int ra = nbx / rw;
  int rn = xcd % ra, rm = xcd / ra;
  int bx = rn * rw + wi % rw;
  int by = rm * rh + wi / rw;

  int m0 = by * 64, n0 = bx * 64;
  int wm = (wid >> 1) * 32, wn = (wid & 1) * 32;
  int rA = tid >> 2, sA = tid & 3;

  floatx4 acc[2][2];
#pragma unroll
  for (int i = 0; i < 2; i++)
#pragma unroll
    for (int j = 0; j < 2; j++) acc[i][j] = (floatx4){0.f, 0.f, 0.f, 0.f};

  int NT = K >> 5;  // 64 K-steps at K=2048
#pragma unroll
  for (int t = 0; t < 2; t++)
    stage_tile64(A, B, lds[t], m0, n0, K, t * 32, wid, rA, sA);

  int cur = 0, sb = 2;
  for (int t = 0; t < NT; t++) {
    if (t < NT - 1) asm volatile("s_waitcnt vmcnt(2)" ::: "memory");
    else            asm volatile("s_waitcnt vmcnt(0)" ::: "memory");
    __builtin_amdgcn_s_barrier();
    __builtin_amdgcn_sched_barrier(0);
    if (t + 2 < NT) {
      stage_tile64(A, B, lds[sb], m0, n0, K, (t + 2) * 32, wid, rA, sA);
      sb = (sb == 2) ? 0 : sb + 1;
    }

    const char* Ab = lds[cur];
    const char* Bb = Ab + 4096;
    cur = (cur == 2) ? 0 : cur + 1;
    shortx8 af[2], bfr[2];
#pragma unroll
    for (int i = 0; i < 2; i++) {
      int r = wm + i * 16 + lrow;
      af[i] = *(const shortx8*)(Ab + r * 64 + ((quad ^ ((r ^ (r >> 2)) & 3)) << 4));
    }
#pragma unroll
    for (int j = 0; j < 2; j++) {
      int r = wn + j * 16 + lrow;
      bfr[j] = *(const shortx8*)(Bb + r * 64 + ((quad ^ ((r ^ (r >> 2)) & 3)) << 4));
    }
    __builtin_amdgcn_s_setprio(1);
#pragma unroll
    for (int i = 0; i < 2; i++)
#pragma unroll
      for (int j = 0; j < 2; j++)
        acc[i][j] = __builtin_amdgcn_mfma_f32_16x16x32_bf16(af[i], bfr[j], acc[i][j], 0, 0, 0);
    __builtin_amdgcn_s_setprio(0);
  }

  bool hasR = (resid != nullptr);
#pragma unroll
  for (int i = 0; i < 2; i++) {
    int r0 = m0 + wm + i * 16 + quad * 4;
#pragma unroll
    for (int j = 0; j < 2; j++) {
      int n = n0 + wn + j * 16 + lrow;
#pragma unroll
      for (int r = 0; r < 4; r++) {
        size_t idx = (size_t)(r0 + r) * N + n;
        float v = acc[i][j][r];
        if (hasR) v += resid[idx];
        C[idx] = v;
      }
    }
  }
}

// ---------------- merged: depthwise conv+silu  ||  dt softplus + chunk cumsum ----------------
__global__ __launch_bounds__(256) void convcum_k(const ushort* __restrict__ zxbf,
                                                 const float* __restrict__ cw,
                                                 const float* __restrict__ cb,
                                                 ushort* __restrict__ xbf,
                                                 const float* __restrict__ dt_bias,
                                                 const float* __restrict__ A_log,
                                                 float* __restrict__ dt_sp,
                                                 float* __restrict__ dtA_cs) {
  __shared__ float buf[256];
  int tid = threadIdx.x;
  if (blockIdx.x < MROWS / 8) {
    // ---- conv + silu ----
    int r0 = blockIdx.x * 8;
    int bstart = r0 & ~(LSEQ - 1);
#pragma unroll
    for (int rep = 0; rep < 2; rep++) {
      int ch;
      if (rep == 0) ch = tid * 8;
      else { if (tid >= (CONVDIM - 2048) / 8) break; ch = 2048 + tid * 8; }
      float wv[8][4], bias[8];
#pragma unroll
      for (int j = 0; j < 8; j++) {
        float4 w4 = *(const float4*)(cw + (ch + j) * 4);
        wv[j][0] = w4.x; wv[j][1] = w4.y; wv[j][2] = w4.z; wv[j][3] = w4.w;
        bias[j] = cb[ch + j];
      }
      float xw[11][8];
#pragma unroll
      for (int wr = 0; wr < 11; wr++) {
        int rr = r0 - 3 + wr;
        if (rr < bstart) {
#pragma unroll
          for (int j = 0; j < 8; j++) xw[wr][j] = 0.f;
        } else {
          shortx8 v = *(const shortx8*)(zxbf + (size_t)rr * DINPROJ + DINNER + ch);
#pragma unroll
          for (int j = 0; j < 8; j++) xw[wr][j] = bf2f((ushort)v[j]);
        }
      }
#pragma unroll
      for (int o = 0; o < 8; o++) {
        shortx8 ov;
#pragma unroll
        for (int j = 0; j < 8; j++) {
          float acc = bias[j];
#pragma unroll
          for (int k = 0; k < 4; k++) acc += xw[o + k][j] * wv[j][k];
          float s = acc / (1.f + expf(-acc));
          ov[j] = (short)f2bf(s);
        }
        *(shortx8*)(xbf + (size_t)(r0 + o) * CONVDIM + ch) = ov;
      }
    }
  } else {
    // ---- dt softplus + per-chunk cumsum ----
    int bid = blockIdx.x - MROWS / 8;  // ((b*8+c)*32+h)
    int h = bid & 31, c = (bid >> 5) & 7, b = bid >> 8;
    int l = tid;
    float Aneg = -expf(A_log[h]);
    int row = b * LSEQ + c * CHUNKSZ + l;
    float v = bf2f(zxbf[(size_t)row * DINPROJ + DINNER + CONVDIM + h]) + dt_bias[h];
    float dtv = (v > 20.f) ? v : log1pf(expf(v));
    dt_sp[row * 32 + h] = dtv;
    buf[l] = dtv * Aneg;
    __syncthreads();
    for (int off = 1; off < 256; off <<= 1) {
      float add = (l >= off) ? buf[l - off] : 0.f;
      __syncthreads();
      buf[l] += add;
      __syncthreads();
    }
    dtA_cs[(size_t)bid * CHUNKSZ + l] = buf[l];
  }
}

// ---------------- MFMA per-chunk end states (vectorized staging, swizzled LDS) ----------------
// Staging: row = tid>>2, seg = tid&3 (16 cols each); 4 shortx8 global loads per
// thread per lt-tile (was 16 uint). Transpose-store col-swizzled with
// key(c) = ((c>>1)&7)<<3 (same involution both sides, rule 21).
#define ST_STRIDE 72
__global__ __launch_bounds__(256) void states_mfma(const ushort* __restrict__ xbf,
                                                   const float* __restrict__ dt_sp,
                                                   const float* __restrict__ dtA_cs,
                                                   float* __restrict__ st_raw) {
  __shared__ ushort XT[64 * ST_STRIDE];  // [p][l'] bf16 (col-swizzled)
  __shared__ ushort BT[64 * ST_STRIDE];  // [n][l'] bf16 (col-swizzled)
  __shared__ float wrow[64];
  int bid = blockIdx.x;  // ((b*8+c)*32+h)
  int h = bid & 31, c = (bid >> 5) & 7, b = bid >> 8;
  int tid = threadIdx.x;
  int w = tid >> 6, lane = tid & 63;
  int quad = lane >> 4, lrow = lane & 15;
  int cbase = bid * CHUNKSZ;
  int rowbase = b * LSEQ + c * CHUNKSZ;
  float T = dtA_cs[cbase + CHUNKSZ - 1];
  floatx4 acc[4];
  for (int jt = 0; jt < 4; jt++) acc[jt] = (floatx4){0.f, 0.f, 0.f, 0.f};
  int row_l = tid >> 2, seg = tid & 3;
  for (int lt = 0; lt < 4; lt++) {
    __syncthreads();
    if (tid < 64) {
      int row = rowbase + lt * 64 + tid;
      wrow[tid] = dt_sp[row * 32 + h] * __expf(T - dtA_cs[cbase + lt * 64 + tid]);
    }
    __syncthreads();
    {
      int row = rowbase + lt * 64 + row_l;
      const ushort* bp = xbf + (size_t)row * CONVDIM + DINNER + seg * 16;
      const ushort* xp = xbf + (size_t)row * CONVDIM + h * DHEAD + seg * 16;
      shortx8 b0 = *(const shortx8*)bp;
      shortx8 b1 = *(const shortx8*)(bp + 8);
      shortx8 x0 = *(const shortx8*)xp;
      shortx8 x1 = *(const shortx8*)(xp + 8);
      float wv = wrow[row_l];
#pragma unroll
      for (int j = 0; j < 8; j++) {
        int c0 = seg * 16 + j;
        int c1 = c0 + 8;
        int k0 = ((c0 >> 1) & 7) << 3;
        int k1 = ((c1 >> 1) & 7) << 3;
        BT[c0 * ST_STRIDE + (row_l ^ k0)] = (ushort)b0[j];
        BT[c1 * ST_STRIDE + (row_l ^ k1)] = (ushort)b1[j];
        XT[c0 * ST_STRIDE + (row_l ^ k0)] = f2bf(bf2f((ushort)x0[j]) * wv);
        XT[c1 * ST_STRIDE + (row_l ^ k1)] = f2bf(bf2f((ushort)x1[j]) * wv);
      }
    }
    __syncthreads();
    int arow = w * 16 + lrow;
    int akey = ((arow >> 1) & 7) << 3;
    for (int kk = 0; kk < 64; kk += 32) {
      shortx8 af = *(const shortx8*)&XT[arow * ST_STRIDE + ((kk + quad * 8) ^ akey)];
      for (int jt = 0; jt < 4; jt++) {
        int brow = jt * 16 + lrow;
        int bkey = ((brow >> 1) & 7) << 3;
        shortx8 bf = *(const shortx8*)&BT[brow * ST_STRIDE + ((kk + quad * 8) ^ bkey)];
        acc[jt] = __builtin_amdgcn_mfma_f32_16x16x32_bf16(af, bf, acc[jt], 0, 0, 0);
      }
    }
  }
  size_t base = (size_t)bid * (DHEAD * DSTATE);
  for (int jt = 0; jt < 4; jt++) {
    int n = jt * 16 + lrow;
    for (int r = 0; r < 4; r++) {
      int p = w * 16 + quad * 4 + r;
      st_raw[base + (size_t)p * 64 + n] = acc[jt][r];
    }
  }
}

// ---------------- inter-chunk scan (in-place, 4-way split) ----------------
__global__ __launch_bounds__(256) void scan_k(float* __restrict__ st,
                                              const float* __restrict__ dtA_cs) {
  int bid = blockIdx.x;              // 256 = b(2) x h(32) x seg(4)
  int seg = bid & 3, h = (bid >> 2) & 31, b = bid >> 7;
  int tid = threadIdx.x;
  int off = seg * 1024;
  float s[4];
  for (int i = 0; i < 4; i++) s[i] = 0.f;
  for (int c = 0; c < NCHUNK; c++) {
    int g = (b * NCHUNK + c) * 32 + h;
    float dec = expf(dtA_cs[(size_t)g * CHUNKSZ + CHUNKSZ - 1]);
    size_t base = (size_t)g * (DHEAD * DSTATE) + off;
    for (int i = 0; i < 4; i++) {
      int idx = tid + i * 256;
      float raw = st[base + idx];
      st[base + idx] = s[i];
      s[i] = s[i] * dec + raw;
    }
  }
}

// ---------------- MFMA ydiag (vectorized staging) ----------------
#define BS_STRIDE 72
#define XT_STRIDE 68
#define PW_STRIDE 72
__global__ __launch_bounds__(256) void ydiag_mfma(const ushort* __restrict__ xbf,
                                                  const float* __restrict__ dt_sp,
                                                  const float* __restrict__ dtA_cs,
                                                  const float* __restrict__ st_in,
                                                  ushort* __restrict__ Y) {
  __shared__ ushort Bs[64 * BS_STRIDE];
  __shared__ ushort XsT[64 * XT_STRIDE];
  __shared__ ushort Pw[4 * 16 * PW_STRIDE];
  __shared__ float cs[256];
  int tid = threadIdx.x;
  int w = tid >> 6, lane = tid & 63;
  int quad = lane >> 4, lrow = lane & 15;
  int bid = blockIdx.x;
  int lt = bid & 3, h = (bid >> 2) & 31, c = (bid >> 7) & 7, b = bid >> 10;
  int g = (b * NCHUNK + c) * 32 + h;
  int cbase = g * CHUNKSZ;
  int rowbase = b * LSEQ + c * CHUNKSZ;

  cs[tid] = dtA_cs[cbase + tid];
  __syncthreads();

  int mrow = lt * 64 + w * 16;
  float csl[4];
  for (int r = 0; r < 4; r++) csl[r] = cs[mrow + quad * 4 + r];

  shortx8 Cf[2];
  {
    const ushort* cp = xbf + (size_t)(rowbase + mrow + lrow) * CONVDIM + DINNER + DSTATE;
    for (int q = 0; q < 2; q++)
      Cf[q] = *(const shortx8*)(cp + q * 32 + quad * 8);
  }

  floatx4 acc[4];
  for (int jt = 0; jt < 4; jt++) acc[jt] = (floatx4){0.f, 0.f, 0.f, 0.f};
  const float* stp = st_in + (size_t)g * (DHEAD * DSTATE);
  for (int q = 0; q < 2; q++) {
    for (int jt = 0; jt < 4; jt++) {
      const float* sp = stp + (size_t)(jt * 16 + lrow) * 64 + q * 32 + quad * 8;
      shortx8 sf = pack8(*(const float4*)sp, *(const float4*)(sp + 4));
      acc[jt] = __builtin_amdgcn_mfma_f32_16x16x32_bf16(Cf[q], sf, acc[jt], 0, 0, 0);
    }
  }
  for (int jt = 0; jt < 4; jt++)
    for (int r = 0; r < 4; r++) acc[jt][r] *= __expf(csl[r]);

  ushort* myP = Pw + w * 16 * PW_STRIDE;
  int row_l = tid >> 2, seg = tid & 3;
  for (int st = 0; st <= lt; st++) {
    __syncthreads();
    {
      int row = rowbase + st * 64 + row_l;
      const ushort* bp = xbf + (size_t)row * CONVDIM + DINNER + seg * 16;
      const ushort* xp = xbf + (size_t)row * CONVDIM + h * DHEAD + seg * 16;
      shortx8 b0 = *(const shortx8*)bp;
      shortx8 b1 = *(const shortx8*)(bp + 8);
      shortx8 x0 = *(const shortx8*)xp;
      shortx8 x1 = *(const shortx8*)(xp + 8);
      float dtv = dt_sp[row * 32 + h];
      *(shortx8*)&Bs[row_l * BS_STRIDE + seg * 16] = b0;
      *(shortx8*)&Bs[row_l * BS_STRIDE + seg * 16 + 8] = b1;
#pragma unroll
      for (int j = 0; j < 8; j++) {
        int c0 = seg * 16 + j;
        XsT[c0 * XT_STRIDE + row_l]       = f2bf(bf2f((ushort)x0[j]) * dtv);
        XsT[(c0 + 8) * XT_STRIDE + row_l] = f2bf(bf2f((ushort)x1[j]) * dtv);
      }
    }
    __syncthreads();
    for (int jt = 0; jt < 4; jt++) {
      floatx4 s = (floatx4){0.f, 0.f, 0.f, 0.f};
      for (int q = 0; q < 2; q++) {
        shortx8 bfr = *(const shortx8*)&Bs[(jt * 16 + lrow) * BS_STRIDE + q * 32 + quad * 8];
        s = __builtin_amdgcn_mfma_f32_16x16x32_bf16(Cf[q], bfr, s, 0, 0, 0);
      }
      int scol = st * 64 + jt * 16 + lrow;
      float css = cs[scol];
      for (int r = 0; r < 4; r++) {
        int l = mrow + quad * 4 + r;
        float v = (scol <= l) ? s[r] * __expf(csl[r] - css) : 0.f;
        myP[(quad * 4 + r) * PW_STRIDE + jt * 16 + lrow] = f2bf(v);
      }
    }
    shortx8 pf[2];
    for (int q = 0; q < 2; q++)
      pf[q] = *(const shortx8*)&myP[lrow * PW_STRIDE + q * 32 + quad * 8];
    for (int jt = 0; jt < 4; jt++) {
      for (int q = 0; q < 2; q++) {
        const ushort* xp = &XsT[(jt * 16 + lrow) * XT_STRIDE + q * 32 + quad * 8];
        shortx4 lo = *(const shortx4*)xp;
        shortx4 hi = *(const shortx4*)(xp + 4);
        shortx8 xf = __builtin_shufflevector(lo, hi, 0, 1, 2, 3, 4, 5, 6, 7);
        acc[jt] = __builtin_amdgcn_mfma_f32_16x16x32_bf16(pf[q], xf, acc[jt], 0, 0, 0);
      }
    }
  }
  int growb = rowbase + mrow + quad * 4;
  for (int jt = 0; jt < 4; jt++)
    for (int r = 0; r < 4; r++)
      Y[(size_t)(growb + r) * DINNER + h * DHEAD + jt * 16 + lrow] = f2bf(acc[jt][r]);
}

// ---------------- gated rmsnorm (+ D*X skip) -> bf16 out (vectorized) ----------------
__global__ __launch_bounds__(256) void gatenorm_k(const ushort* __restrict__ Ybf,
                                                  const ushort* __restrict__ zxbf,
                                                  const ushort* __restrict__ xbf,
                                                  const float* __restrict__ Dvec,
                                                  const float* __restrict__ gw,
                                                  ushort* __restrict__ obf) {
  __shared__ float sb[4];
  int r = blockIdx.x;
  int c0 = threadIdx.x * 8;
  const ushort* yr = Ybf + (size_t)r * DINNER;
  const ushort* zr = zxbf + (size_t)r * DINPROJ;
  const ushort* xr = xbf + (size_t)r * CONVDIM;
  ushort* orow = obf + (size_t)r * DINNER;
  shortx8 y8 = *(const shortx8*)(yr + c0);
  shortx8 z8 = *(const shortx8*)(zr + c0);
  shortx8 x8 = *(const shortx8*)(xr + c0);
  float Dv = Dvec[threadIdx.x >> 3];   // 8 cols per thread stay in one head
  float t[8]; float ssq = 0.f;
#pragma unroll
  for (int i = 0; i < 8; i++) {
    float z = bf2f((ushort)z8[i]);
    float yv = bf2f((ushort)y8[i]) + Dv * bf2f((ushort)x8[i]);
    float gv = yv * (z / (1.f + expf(-z)));
    t[i] = gv;
    ssq += gv * gv;
  }
  float s = block_reduce_sum_256(ssq, sb);
  float sc = rsqrtf(s / (float)DINNER + EPSF);
  float4 g0 = *(const float4*)(gw + c0);
  float4 g1 = *(const float4*)(gw + c0 + 4);
  shortx8 o;
  o[0] = (short)f2bf(t[0] * sc * g0.x); o[1] = (short)f2bf(t[1] * sc * g0.y);
  o[2] = (short)f2bf(t[2] * sc * g0.z); o[3] = (short)f2bf(t[3] * sc * g0.w);
  o[4] = (short)f2bf(t[4] * sc * g1.x); o[5] = (short)f2bf(t[5] * sc * g1.y);
  o[6] = (short)f2bf(t[6] * sc * g1.z); o[7] = (short)f2bf(t[7] * sc * g1.w);
  *(shortx8*)(orow + c0) = o;
}

// ---------------- launch ----------------
extern "C" void kernel_launch(void* const* d_in, const int* in_sizes, int n_in,
                              void* d_out, int out_size, void* d_ws, size_t ws_size,
                              hipStream_t stream) {
  const float* x_in     = (const float*)d_in[0];
  const float* in_w     = (const float*)d_in[1];
  const float* conv_w   = (const float*)d_in[2];
  const float* conv_b   = (const float*)d_in[3];
  const float* dt_bias  = (const float*)d_in[4];
  const float* A_log    = (const float*)d_in[5];
  const float* Dvec     = (const float*)d_in[6];
  const float* gnorm_w  = (const float*)d_in[7];
  const float* out_w    = (const float*)d_in[8];
  const float* rms_w    = (const float*)d_in[9];
  float* out = (float*)d_out;

  float* ws = (float*)d_ws;
  size_t o = 0;
  float* x_cur  = ws + o; o += (size_t)MROWS * DMODEL;
  ushort* zx_bf = (ushort*)(ws + o); o += (size_t)MROWS * DINPROJ / 2;
  ushort* xbf   = (ushort*)(ws + o); o += (size_t)MROWS * CONVDIM / 2;
  float* dt_sp  = ws + o; o += (size_t)MROWS * NHEADS;
  float* dtA_cs = ws + o; o += (size_t)BATCH * NCHUNK * NHEADS * CHUNKSZ;
  float* st     = ws + o; o += (size_t)BATCH * NCHUNK * NHEADS * DHEAD * DSTATE;
  ushort* Ybf   = (ushort*)(ws + o); o += (size_t)MROWS * DINNER / 2;
  ushort* act_bf = (ushort*)(ws + o); o += (size_t)MROWS * DINNER / 2;
  size_t base_f = o;

  // hoisted weight area (all 4 layers)
  size_t inw_f  = (size_t)4 * DINPROJ_PAD * DMODEL / 2;  // 8,912,896 floats
  size_t outw_f = (size_t)4 * DMODEL * DINNER / 2;       // 4,194,304 floats
  bool hoist = ws_size >= (base_f + inw_f + outw_f) * sizeof(float);

  ushort* in_bf_all = (ushort*)(ws + base_f);
  ushort* out_bf_all = (ushort*)(ws + base_f + inw_f);
  ushort* w_bf_fb = (ushort*)(ws + base_f);  // fallback: single-layer buffer

  hipMemcpyAsync(x_cur, x_in, (size_t)MROWS * DMODEL * sizeof(float),
                 hipMemcpyDeviceToDevice, stream);

  if (hoist) {
    unsigned ntot = (4u * DINPROJ_PAD * DMODEL + 4u * DMODEL * DINNER) / 8u;
    cvt_w_all<<<(ntot + 255) / 256, 256, 0, stream>>>(in_w, out_w, in_bf_all, out_bf_all);
  }

  for (int i = 0; i < 4; i++) {
    const float* conv_w_i = conv_w  + (size_t)i * CONVDIM * DCONV;
    const float* conv_b_i = conv_b  + (size_t)i * CONVDIM;
    const float* dtb_i    = dt_bias + (size_t)i * NHEADS;
    const float* Alog_i   = A_log   + (size_t)i * NHEADS;
    const float* D_i      = Dvec    + (size_t)i * NHEADS;
    const float* gw_i     = gnorm_w + (size_t)i * DINNER;
    const float* rms_w_i  = rms_w   + (size_t)i * DMODEL;

    const ushort* w1_bf;
    const ushort* w2_bf;
    if (hoist) {
      w1_bf = in_bf_all  + (size_t)i * DINPROJ_PAD * DMODEL;
      w2_bf = out_bf_all + (size_t)i * DMODEL * DINNER;
    } else {
      size_t ns = (size_t)DINPROJ * DMODEL, nd = (size_t)DINPROJ_PAD * DMODEL;
      cvt_bf16_k<<<(nd + 255) / 256, 256, 0, stream>>>(
          in_w + (size_t)i * DINPROJ * DMODEL, w_bf_fb, ns, nd);
      w1_bf = w_bf_fb;
      w2_bf = w_bf_fb;
    }

    rmsnorm_k<<<MROWS, 256, 0, stream>>>(x_cur, rms_w_i, act_bf);
    // GEMM1: grid 34x32 = 1088 blocks; XCD region = 17 x 8 tiles.
    gemm_nt_mfma_pipe<<<(DINPROJ_PAD / 128) * (MROWS / 128), 256, 0, stream>>>(
        act_bf, w1_bf, zx_bf, MROWS, DINPROJ, DMODEL, DINPROJ_PAD / 128, 17, 8);
    convcum_k<<<MROWS / 8 + BATCH * NCHUNK * NHEADS, 256, 0, stream>>>(
        zx_bf, conv_w_i, conv_b_i, xbf, dtb_i, Alog_i, dt_sp, dtA_cs);
    states_mfma<<<BATCH * NCHUNK * NHEADS, 256, 0, stream>>>(xbf, dt_sp, dtA_cs, st);
    scan_k<<<BATCH * NHEADS * 4, 256, 0, stream>>>(st, dtA_cs);
    ydiag_mfma<<<BATCH * NCHUNK * NHEADS * 4, 256, 0, stream>>>(
        xbf, dt_sp, dtA_cs, st, Ybf);
    gatenorm_k<<<MROWS, 256, 0, stream>>>(Ybf, zx_bf, xbf, D_i, gw_i, act_bf);
    if (!hoist) {
      size_t ns = (size_t)DMODEL * DINNER;
      cvt_bf16_k<<<(ns + 255) / 256, 256, 0, stream>>>(
          out_w + (size_t)i * DMODEL * DINNER, (ushort*)w_bf_fb, ns, ns);
    }
    float* outC = (i == 3) ? out : x_cur;
    // GEMM2: 64x64 tiles -> grid 64x16 = 1024 blocks = 4 blocks/CU;
    // XCD region = 8 x 16 tiles (nbx=16, ra=2).
    gemm_nt_64<<<(MROWS / 64) * (DMODEL / 64), 256, 0, stream>>>(
        act_bf, w2_bf, outC, x_cur, MROWS, DMODEL, DINNER, DMODEL / 64, 8, 16);
  }
}

// Round 9
// 868.649 us; speedup vs baseline: 1.0418x; 1.0418x over previous
//
#include <hip/hip_runtime.h>
#include <cmath>

#define BATCH 2
#define LSEQ 2048
#define DMODEL 1024
#define DINNER 2048
#define NHEADS 32
#define DHEAD 64
#define DSTATE 64
#define DCONV 4
#define CONVDIM (DINNER + 2*DSTATE)            // 2176
#define DINPROJ (2*DINNER + 2*DSTATE + NHEADS) // 4256
#define DINPROJ_PAD 4352                       // 34*128
#define CHUNKSZ 256
#define NCHUNK (LSEQ/CHUNKSZ)                  // 8
#define MROWS (BATCH*LSEQ)                     // 4096
#define EPSF 1e-5f

typedef __attribute__((ext_vector_type(8))) short shortx8;
typedef __attribute__((ext_vector_type(4))) short shortx4;
typedef __attribute__((ext_vector_type(4))) float floatx4;

__device__ __forceinline__ ushort f2bf(float f) {
  unsigned u = __float_as_uint(f);
  unsigned r = (u + 0x7fffu + ((u >> 16) & 1u)) >> 16;
  return (ushort)r;
}
__device__ __forceinline__ float bf2f(ushort b) {
  return __uint_as_float(((unsigned)b) << 16);
}

__device__ __forceinline__ shortx8 pack8(float4 a, float4 b) {
  shortx8 r;
  r[0] = (short)f2bf(a.x); r[1] = (short)f2bf(a.y);
  r[2] = (short)f2bf(a.z); r[3] = (short)f2bf(a.w);
  r[4] = (short)f2bf(b.x); r[5] = (short)f2bf(b.y);
  r[6] = (short)f2bf(b.z); r[7] = (short)f2bf(b.w);
  return r;
}

__device__ __forceinline__ void async_load16(const void* g, void* l) {
  __builtin_amdgcn_global_load_lds(
      (const __attribute__((address_space(1))) void*)g,
      (__attribute__((address_space(3))) void*)l, 16, 0, 0);
}

// ---------------- reductions ----------------
__device__ __forceinline__ float block_reduce_sum_256(float v, float* sb) {
  for (int off = 32; off > 0; off >>= 1) v += __shfl_down(v, off, 64);
  int lane = threadIdx.x & 63, wid = threadIdx.x >> 6;
  if (lane == 0) sb[wid] = v;
  __syncthreads();
  return sb[0] + sb[1] + sb[2] + sb[3];
}

// ---------------- fp32 -> bf16 (with zero tail padding), per-layer fallback ----------------
__global__ __launch_bounds__(256) void cvt_bf16_k(const float* __restrict__ src,
                                                  ushort* __restrict__ dst,
                                                  size_t n_src, size_t n_dst) {
  size_t i = (size_t)blockIdx.x * 256 + threadIdx.x;
  if (i >= n_dst) return;
  float v = (i < n_src) ? src[i] : 0.f;
  dst[i] = f2bf(v);
}

// ---------------- ALL-layer weight cvt (hoisted, vectorized 8 elem/thread) ----------------
__global__ __launch_bounds__(256) void cvt_w_all(const float* __restrict__ in_w,
                                                 const float* __restrict__ out_w,
                                                 ushort* __restrict__ in_bf,
                                                 ushort* __restrict__ out_bf) {
  unsigned g = (blockIdx.x * 256u + threadIdx.x) * 8u;
  const unsigned PL = (unsigned)DINPROJ_PAD * DMODEL;         // 4,456,448
  const unsigned n1 = 4u * PL;                                 // 17,825,792
  const unsigned n2 = 4u * DMODEL * DINNER;                    // 8,388,608
  if (g < n1) {
    unsigned layer = g / PL, rem = g % PL;
    unsigned row = rem / DMODEL, col = rem % DMODEL;  // col 8-aligned, in-row
    shortx8 o;
    if (row < DINPROJ) {
      const float* sp = in_w + ((size_t)layer * DINPROJ + row) * DMODEL + col;
      float4 a = *(const float4*)sp;
      float4 b = *(const float4*)(sp + 4);
      o = pack8(a, b);
    } else {
#pragma unroll
      for (int j = 0; j < 8; j++) o[j] = 0;
    }
    *(shortx8*)(in_bf + g) = o;
  } else if (g < n1 + n2) {
    unsigned j = g - n1;
    const float* sp = out_w + j;
    float4 a = *(const float4*)sp;
    float4 b = *(const float4*)(sp + 4);
    *(shortx8*)(out_bf + j) = pack8(a, b);
  }
}

// ---------------- rmsnorm (width 1024) -> bf16 out (vectorized) ----------------
__global__ __launch_bounds__(256) void rmsnorm_k(const float* __restrict__ x,
                                                 const float* __restrict__ w,
                                                 ushort* __restrict__ out) {
  __shared__ float sb[4];
  int r = blockIdx.x;
  const float* xr = x + (size_t)r * DMODEL;
  ushort* orow = out + (size_t)r * DMODEL;
  int c0 = threadIdx.x * 4;
  float4 v4 = *(const float4*)(xr + c0);
  float ssq = v4.x * v4.x + v4.y * v4.y + v4.z * v4.z + v4.w * v4.w;
  float s = block_reduce_sum_256(ssq, sb);
  float sc = rsqrtf(s / (float)DMODEL + EPSF);
  float4 w4 = *(const float4*)(w + c0);
  shortx4 o;
  o[0] = (short)f2bf(v4.x * sc * w4.x);
  o[1] = (short)f2bf(v4.y * sc * w4.y);
  o[2] = (short)f2bf(v4.z * sc * w4.z);
  o[3] = (short)f2bf(v4.w * sc * w4.w);
  *(shortx4*)(orow + c0) = o;
}

// ---------------- pipelined MFMA bf16 NT GEMM, 128x128 tile (GEMM1) ----------------
__device__ __forceinline__ void stage_tile(const ushort* __restrict__ A,
                                           const ushort* __restrict__ B,
                                           char* lb, int m0, int n0, int K, int k0,
                                           int wid, int rA, int sA) {
#pragma unroll
  for (int rd = 0; rd < 2; rd++) {
    int r = rd * 64 + rA;
    int sl = sA ^ ((r ^ (r >> 2)) & 3);
    async_load16(A + (size_t)(m0 + r) * K + (k0 + sl * 8), lb + rd * 4096 + wid * 1024);
  }
#pragma unroll
  for (int rd = 0; rd < 2; rd++) {
    int r = rd * 64 + rA;
    int sl = sA ^ ((r ^ (r >> 2)) & 3);
    async_load16(B + (size_t)(n0 + r) * K + (k0 + sl * 8), lb + 8192 + rd * 4096 + wid * 1024);
  }
}

__global__ __launch_bounds__(256, 3) void gemm_nt_mfma_pipe(
    const ushort* __restrict__ A, const ushort* __restrict__ B,
    ushort* __restrict__ Cbf, int M, int N, int K,
    int nbx, int rw, int rh) {
  __shared__ __align__(16) char lds[3][16384];
  int tid = threadIdx.x;
  int wid = tid >> 6, lane = tid & 63;
  int quad = lane >> 4, lrow = lane & 15;

  int d = blockIdx.x;
  int xcd = d & 7, wi = d >> 3;
  int ra = nbx / rw;
  int rn = xcd % ra, rm = xcd / ra;
  int bx = rn * rw + wi % rw;
  int by = rm * rh + wi / rw;

  int m0 = by * 128, n0 = bx * 128;
  int wm = (wid >> 1) * 64, wn = (wid & 1) * 64;
  int rA = tid >> 2, sA = tid & 3;

  floatx4 acc[4][4];
#pragma unroll
  for (int i = 0; i < 4; i++)
#pragma unroll
    for (int j = 0; j < 4; j++) acc[i][j] = (floatx4){0.f, 0.f, 0.f, 0.f};

  int NT = K >> 5;
#pragma unroll
  for (int t = 0; t < 2; t++)
    stage_tile(A, B, lds[t], m0, n0, K, t * 32, wid, rA, sA);

  int cur = 0, sb = 2;
  for (int t = 0; t < NT; t++) {
    if (t < NT - 1) asm volatile("s_waitcnt vmcnt(4)" ::: "memory");
    else            asm volatile("s_waitcnt vmcnt(0)" ::: "memory");
    __builtin_amdgcn_s_barrier();
    __builtin_amdgcn_sched_barrier(0);
    if (t + 2 < NT) {
      stage_tile(A, B, lds[sb], m0, n0, K, (t + 2) * 32, wid, rA, sA);
      sb = (sb == 2) ? 0 : sb + 1;
    }

    const char* Ab = lds[cur];
    const char* Bb = Ab + 8192;
    cur = (cur == 2) ? 0 : cur + 1;
    shortx8 af[4], bfr[4];
#pragma unroll
    for (int i = 0; i < 4; i++) {
      int r = wm + i * 16 + lrow;
      af[i] = *(const shortx8*)(Ab + r * 64 + ((quad ^ ((r ^ (r >> 2)) & 3)) << 4));
    }
#pragma unroll
    for (int j = 0; j < 4; j++) {
      int r = wn + j * 16 + lrow;
      bfr[j] = *(const shortx8*)(Bb + r * 64 + ((quad ^ ((r ^ (r >> 2)) & 3)) << 4));
    }
    __builtin_amdgcn_s_setprio(1);
#pragma unroll
    for (int i = 0; i < 4; i++)
#pragma unroll
      for (int j = 0; j < 4; j++)
        acc[i][j] = __builtin_amdgcn_mfma_f32_16x16x32_bf16(af[i], bfr[j], acc[i][j], 0, 0, 0);
    __builtin_amdgcn_s_setprio(0);
  }

#pragma unroll
  for (int i = 0; i < 4; i++) {
    int r0 = m0 + wm + i * 16 + quad * 4;
#pragma unroll
    for (int j = 0; j < 4; j++) {
      int n = n0 + wn + j * 16 + lrow;
      if (n < N)
#pragma unroll
        for (int r = 0; r < 4; r++)
          Cbf[(size_t)(r0 + r) * N + n] = f2bf(acc[i][j][r]);
    }
  }
}

// ---------------- pipelined MFMA bf16 NT GEMM, 128x64 tile (GEMM2, R7 proven) ----------------
// Grid 512 blocks = 2 blocks/CU = 8 waves/CU. 3 LDS buffers x 12 KB;
// 3 loads/thread/stage -> steady vmcnt(3). (R8's 64x64 retile regressed:
// 4 blocks/CU gained TLP but halved arithmetic intensity -> net loss.)
__device__ __forceinline__ void stage_tile64(const ushort* __restrict__ A,
                                             const ushort* __restrict__ B,
                                             char* lb, int m0, int n0, int K, int k0,
                                             int wid, int rA, int sA) {
#pragma unroll
  for (int rd = 0; rd < 2; rd++) {
    int r = rd * 64 + rA;
    int sl = sA ^ ((r ^ (r >> 2)) & 3);
    async_load16(A + (size_t)(m0 + r) * K + (k0 + sl * 8), lb + rd * 4096 + wid * 1024);
  }
  {
    int r = rA;
    int sl = sA ^ ((r ^ (r >> 2)) & 3);
    async_load16(B + (size_t)(n0 + r) * K + (k0 + sl * 8), lb + 8192 + wid * 1024);
  }
}

__global__ __launch_bounds__(256, 2) void gemm_nt_64(
    const ushort* __restrict__ A, const ushort* __restrict__ B,
    float* __restrict__ C, const float* __restrict__ resid,
    int M, int N, int K, int nbx, int rw, int rh) {
  __shared__ __align__(16) char lds[3][12288];
  int tid = threadIdx.x;
  int wid = tid >> 6, lane = tid & 63;
  int quad = lane >> 4, lrow = lane & 15;

  int d = blockIdx.x;
  int xcd = d & 7, wi = d >> 3;
  int ra = nbx / rw;
  int rn = xcd % ra, rm = xcd / ra;
  int bx = rn * rw + wi % rw;
  int by = rm * rh + wi / rw;

  int m0 = by * 128, n0 = bx * 64;
  int wm = (wid >> 1) * 64, wn = (wid & 1) * 32;
  int rA = tid >> 2, sA = tid & 3;

  floatx4 acc[4][2];
#pragma unroll
  for (int i = 0; i < 4; i++)
#pragma unroll
    for (int j = 0; j < 2; j++) acc[i][j] = (floatx4){0.f, 0.f, 0.f, 0.f};

  int NT = K >> 5;
#pragma unroll
  for (int t = 0; t < 2; t++)
    stage_tile64(A, B, lds[t], m0, n0, K, t * 32, wid, rA, sA);

  int cur = 0, sb = 2;
  for (int t = 0; t < NT; t++) {
    if (t < NT - 1) asm volatile("s_waitcnt vmcnt(3)" ::: "memory");
    else            asm volatile("s_waitcnt vmcnt(0)" ::: "memory");
    __builtin_amdgcn_s_barrier();
    __builtin_amdgcn_sched_barrier(0);
    if (t + 2 < NT) {
      stage_tile64(A, B, lds[sb], m0, n0, K, (t + 2) * 32, wid, rA, sA);
      sb = (sb == 2) ? 0 : sb + 1;
    }

    const char* Ab = lds[cur];
    const char* Bb = Ab + 8192;
    cur = (cur == 2) ? 0 : cur + 1;
    shortx8 af[4], bfr[2];
#pragma unroll
    for (int i = 0; i < 4; i++) {
      int r = wm + i * 16 + lrow;
      af[i] = *(const shortx8*)(Ab + r * 64 + ((quad ^ ((r ^ (r >> 2)) & 3)) << 4));
    }
#pragma unroll
    for (int j = 0; j < 2; j++) {
      int r = wn + j * 16 + lrow;
      bfr[j] = *(const shortx8*)(Bb + r * 64 + ((quad ^ ((r ^ (r >> 2)) & 3)) << 4));
    }
    __builtin_amdgcn_s_setprio(1);
#pragma unroll
    for (int i = 0; i < 4; i++)
#pragma unroll
      for (int j = 0; j < 2; j++)
        acc[i][j] = __builtin_amdgcn_mfma_f32_16x16x32_bf16(af[i], bfr[j], acc[i][j], 0, 0, 0);
    __builtin_amdgcn_s_setprio(0);
  }

  bool hasR = (resid != nullptr);
#pragma unroll
  for (int i = 0; i < 4; i++) {
    int r0 = m0 + wm + i * 16 + quad * 4;
#pragma unroll
    for (int j = 0; j < 2; j++) {
      int n = n0 + wn + j * 16 + lrow;
#pragma unroll
      for (int r = 0; r < 4; r++) {
        size_t idx = (size_t)(r0 + r) * N + n;
        float v = acc[i][j][r];
        if (hasR) v += resid[idx];
        C[idx] = v;
      }
    }
  }
}

// ---------------- merged: depthwise conv+silu  ||  dt softplus + chunk cumsum ----------------
__global__ __launch_bounds__(256) void convcum_k(const ushort* __restrict__ zxbf,
                                                 const float* __restrict__ cw,
                                                 const float* __restrict__ cb,
                                                 ushort* __restrict__ xbf,
                                                 const float* __restrict__ dt_bias,
                                                 const float* __restrict__ A_log,
                                                 float* __restrict__ dt_sp,
                                                 float* __restrict__ dtA_cs) {
  __shared__ float buf[256];
  int tid = threadIdx.x;
  if (blockIdx.x < MROWS / 8) {
    // ---- conv + silu ----
    int r0 = blockIdx.x * 8;
    int bstart = r0 & ~(LSEQ - 1);
#pragma unroll
    for (int rep = 0; rep < 2; rep++) {
      int ch;
      if (rep == 0) ch = tid * 8;
      else { if (tid >= (CONVDIM - 2048) / 8) break; ch = 2048 + tid * 8; }
      float wv[8][4], bias[8];
#pragma unroll
      for (int j = 0; j < 8; j++) {
        float4 w4 = *(const float4*)(cw + (ch + j) * 4);
        wv[j][0] = w4.x; wv[j][1] = w4.y; wv[j][2] = w4.z; wv[j][3] = w4.w;
        bias[j] = cb[ch + j];
      }
      float xw[11][8];
#pragma unroll
      for (int wr = 0; wr < 11; wr++) {
        int rr = r0 - 3 + wr;
        if (rr < bstart) {
#pragma unroll
          for (int j = 0; j < 8; j++) xw[wr][j] = 0.f;
        } else {
          shortx8 v = *(const shortx8*)(zxbf + (size_t)rr * DINPROJ + DINNER + ch);
#pragma unroll
          for (int j = 0; j < 8; j++) xw[wr][j] = bf2f((ushort)v[j]);
        }
      }
#pragma unroll
      for (int o = 0; o < 8; o++) {
        shortx8 ov;
#pragma unroll
        for (int j = 0; j < 8; j++) {
          float acc = bias[j];
#pragma unroll
          for (int k = 0; k < 4; k++) acc += xw[o + k][j] * wv[j][k];
          float s = acc / (1.f + expf(-acc));
          ov[j] = (short)f2bf(s);
        }
        *(shortx8*)(xbf + (size_t)(r0 + o) * CONVDIM + ch) = ov;
      }
    }
  } else {
    // ---- dt softplus + per-chunk cumsum ----
    int bid = blockIdx.x - MROWS / 8;  // ((b*8+c)*32+h)
    int h = bid & 31, c = (bid >> 5) & 7, b = bid >> 8;
    int l = tid;
    float Aneg = -expf(A_log[h]);
    int row = b * LSEQ + c * CHUNKSZ + l;
    float v = bf2f(zxbf[(size_t)row * DINPROJ + DINNER + CONVDIM + h]) + dt_bias[h];
    float dtv = (v > 20.f) ? v : log1pf(expf(v));
    dt_sp[row * 32 + h] = dtv;
    buf[l] = dtv * Aneg;
    __syncthreads();
    for (int off = 1; off < 256; off <<= 1) {
      float add = (l >= off) ? buf[l - off] : 0.f;
      __syncthreads();
      buf[l] += add;
      __syncthreads();
    }
    dtA_cs[(size_t)bid * CHUNKSZ + l] = buf[l];
  }
}

// ---------------- MFMA per-chunk end states (vectorized staging, swizzled LDS) ----------------
#define ST_STRIDE 72
__global__ __launch_bounds__(256) void states_mfma(const ushort* __restrict__ xbf,
                                                   const float* __restrict__ dt_sp,
                                                   const float* __restrict__ dtA_cs,
                                                   float* __restrict__ st_raw) {
  __shared__ ushort XT[64 * ST_STRIDE];  // [p][l'] bf16 (col-swizzled)
  __shared__ ushort BT[64 * ST_STRIDE];  // [n][l'] bf16 (col-swizzled)
  __shared__ float wrow[64];
  int bid = blockIdx.x;  // ((b*8+c)*32+h)
  int h = bid & 31, c = (bid >> 5) & 7, b = bid >> 8;
  int tid = threadIdx.x;
  int w = tid >> 6, lane = tid & 63;
  int quad = lane >> 4, lrow = lane & 15;
  int cbase = bid * CHUNKSZ;
  int rowbase = b * LSEQ + c * CHUNKSZ;
  float T = dtA_cs[cbase + CHUNKSZ - 1];
  floatx4 acc[4];
  for (int jt = 0; jt < 4; jt++) acc[jt] = (floatx4){0.f, 0.f, 0.f, 0.f};
  int row_l = tid >> 2, seg = tid & 3;
  for (int lt = 0; lt < 4; lt++) {
    __syncthreads();
    if (tid < 64) {
      int row = rowbase + lt * 64 + tid;
      wrow[tid] = dt_sp[row * 32 + h] * __expf(T - dtA_cs[cbase + lt * 64 + tid]);
    }
    __syncthreads();
    {
      int row = rowbase + lt * 64 + row_l;
      const ushort* bp = xbf + (size_t)row * CONVDIM + DINNER + seg * 16;
      const ushort* xp = xbf + (size_t)row * CONVDIM + h * DHEAD + seg * 16;
      shortx8 b0 = *(const shortx8*)bp;
      shortx8 b1 = *(const shortx8*)(bp + 8);
      shortx8 x0 = *(const shortx8*)xp;
      shortx8 x1 = *(const shortx8*)(xp + 8);
      float wv = wrow[row_l];
#pragma unroll
      for (int j = 0; j < 8; j++) {
        int c0 = seg * 16 + j;
        int c1 = c0 + 8;
        int k0 = ((c0 >> 1) & 7) << 3;
        int k1 = ((c1 >> 1) & 7) << 3;
        BT[c0 * ST_STRIDE + (row_l ^ k0)] = (ushort)b0[j];
        BT[c1 * ST_STRIDE + (row_l ^ k1)] = (ushort)b1[j];
        XT[c0 * ST_STRIDE + (row_l ^ k0)] = f2bf(bf2f((ushort)x0[j]) * wv);
        XT[c1 * ST_STRIDE + (row_l ^ k1)] = f2bf(bf2f((ushort)x1[j]) * wv);
      }
    }
    __syncthreads();
    int arow = w * 16 + lrow;
    int akey = ((arow >> 1) & 7) << 3;
    for (int kk = 0; kk < 64; kk += 32) {
      shortx8 af = *(const shortx8*)&XT[arow * ST_STRIDE + ((kk + quad * 8) ^ akey)];
      for (int jt = 0; jt < 4; jt++) {
        int brow = jt * 16 + lrow;
        int bkey = ((brow >> 1) & 7) << 3;
        shortx8 bf = *(const shortx8*)&BT[brow * ST_STRIDE + ((kk + quad * 8) ^ bkey)];
        acc[jt] = __builtin_amdgcn_mfma_f32_16x16x32_bf16(af, bf, acc[jt], 0, 0, 0);
      }
    }
  }
  size_t base = (size_t)bid * (DHEAD * DSTATE);
  for (int jt = 0; jt < 4; jt++) {
    int n = jt * 16 + lrow;
    for (int r = 0; r < 4; r++) {
      int p = w * 16 + quad * 4 + r;
      st_raw[base + (size_t)p * 64 + n] = acc[jt][r];
    }
  }
}

// ---------------- inter-chunk scan (in-place, 4-way split) ----------------
__global__ __launch_bounds__(256) void scan_k(float* __restrict__ st,
                                              const float* __restrict__ dtA_cs) {
  int bid = blockIdx.x;              // 256 = b(2) x h(32) x seg(4)
  int seg = bid & 3, h = (bid >> 2) & 31, b = bid >> 7;
  int tid = threadIdx.x;
  int off = seg * 1024;
  float s[4];
  for (int i = 0; i < 4; i++) s[i] = 0.f;
  for (int c = 0; c < NCHUNK; c++) {
    int g = (b * NCHUNK + c) * 32 + h;
    float dec = expf(dtA_cs[(size_t)g * CHUNKSZ + CHUNKSZ - 1]);
    size_t base = (size_t)g * (DHEAD * DSTATE) + off;
    for (int i = 0; i < 4; i++) {
      int idx = tid + i * 256;
      float raw = st[base + idx];
      st[base + idx] = s[i];
      s[i] = s[i] * dec + raw;
    }
  }
}

// ---------------- MFMA ydiag (vectorized staging) ----------------
#define BS_STRIDE 72
#define XT_STRIDE 68
#define PW_STRIDE 72
__global__ __launch_bounds__(256) void ydiag_mfma(const ushort* __restrict__ xbf,
                                                  const float* __restrict__ dt_sp,
                                                  const float* __restrict__ dtA_cs,
                                                  const float* __restrict__ st_in,
                                                  ushort* __restrict__ Y) {
  __shared__ ushort Bs[64 * BS_STRIDE];
  __shared__ ushort XsT[64 * XT_STRIDE];
  __shared__ ushort Pw[4 * 16 * PW_STRIDE];
  __shared__ float cs[256];
  int tid = threadIdx.x;
  int w = tid >> 6, lane = tid & 63;
  int quad = lane >> 4, lrow = lane & 15;
  int bid = blockIdx.x;
  int lt = bid & 3, h = (bid >> 2) & 31, c = (bid >> 7) & 7, b = bid >> 10;
  int g = (b * NCHUNK + c) * 32 + h;
  int cbase = g * CHUNKSZ;
  int rowbase = b * LSEQ + c * CHUNKSZ;

  cs[tid] = dtA_cs[cbase + tid];
  __syncthreads();

  int mrow = lt * 64 + w * 16;
  float csl[4];
  for (int r = 0; r < 4; r++) csl[r] = cs[mrow + quad * 4 + r];

  shortx8 Cf[2];
  {
    const ushort* cp = xbf + (size_t)(rowbase + mrow + lrow) * CONVDIM + DINNER + DSTATE;
    for (int q = 0; q < 2; q++)
      Cf[q] = *(const shortx8*)(cp + q * 32 + quad * 8);
  }

  floatx4 acc[4];
  for (int jt = 0; jt < 4; jt++) acc[jt] = (floatx4){0.f, 0.f, 0.f, 0.f};
  const float* stp = st_in + (size_t)g * (DHEAD * DSTATE);
  for (int q = 0; q < 2; q++) {
    for (int jt = 0; jt < 4; jt++) {
      const float* sp = stp + (size_t)(jt * 16 + lrow) * 64 + q * 32 + quad * 8;
      shortx8 sf = pack8(*(const float4*)sp, *(const float4*)(sp + 4));
      acc[jt] = __builtin_amdgcn_mfma_f32_16x16x32_bf16(Cf[q], sf, acc[jt], 0, 0, 0);
    }
  }
  for (int jt = 0; jt < 4; jt++)
    for (int r = 0; r < 4; r++) acc[jt][r] *= __expf(csl[r]);

  ushort* myP = Pw + w * 16 * PW_STRIDE;
  int row_l = tid >> 2, seg = tid & 3;
  for (int st = 0; st <= lt; st++) {
    __syncthreads();
    {
      int row = rowbase + st * 64 + row_l;
      const ushort* bp = xbf + (size_t)row * CONVDIM + DINNER + seg * 16;
      const ushort* xp = xbf + (size_t)row * CONVDIM + h * DHEAD + seg * 16;
      shortx8 b0 = *(const shortx8*)bp;
      shortx8 b1 = *(const shortx8*)(bp + 8);
      shortx8 x0 = *(const shortx8*)xp;
      shortx8 x1 = *(const shortx8*)(xp + 8);
      float dtv = dt_sp[row * 32 + h];
      *(shortx8*)&Bs[row_l * BS_STRIDE + seg * 16] = b0;
      *(shortx8*)&Bs[row_l * BS_STRIDE + seg * 16 + 8] = b1;
#pragma unroll
      for (int j = 0; j < 8; j++) {
        int c0 = seg * 16 + j;
        XsT[c0 * XT_STRIDE + row_l]       = f2bf(bf2f((ushort)x0[j]) * dtv);
        XsT[(c0 + 8) * XT_STRIDE + row_l] = f2bf(bf2f((ushort)x1[j]) * dtv);
      }
    }
    __syncthreads();
    for (int jt = 0; jt < 4; jt++) {
      floatx4 s = (floatx4){0.f, 0.f, 0.f, 0.f};
      for (int q = 0; q < 2; q++) {
        shortx8 bfr = *(const shortx8*)&Bs[(jt * 16 + lrow) * BS_STRIDE + q * 32 + quad * 8];
        s = __builtin_amdgcn_mfma_f32_16x16x32_bf16(Cf[q], bfr, s, 0, 0, 0);
      }
      int scol = st * 64 + jt * 16 + lrow;
      float css = cs[scol];
      for (int r = 0; r < 4; r++) {
        int l = mrow + quad * 4 + r;
        float v = (scol <= l) ? s[r] * __expf(csl[r] - css) : 0.f;
        myP[(quad * 4 + r) * PW_STRIDE + jt * 16 + lrow] = f2bf(v);
      }
    }
    shortx8 pf[2];
    for (int q = 0; q < 2; q++)
      pf[q] = *(const shortx8*)&myP[lrow * PW_STRIDE + q * 32 + quad * 8];
    for (int jt = 0; jt < 4; jt++) {
      for (int q = 0; q < 2; q++) {
        const ushort* xp = &XsT[(jt * 16 + lrow) * XT_STRIDE + q * 32 + quad * 8];
        shortx4 lo = *(const shortx4*)xp;
        shortx4 hi = *(const shortx4*)(xp + 4);
        shortx8 xf = __builtin_shufflevector(lo, hi, 0, 1, 2, 3, 4, 5, 6, 7);
        acc[jt] = __builtin_amdgcn_mfma_f32_16x16x32_bf16(pf[q], xf, acc[jt], 0, 0, 0);
      }
    }
  }
  int growb = rowbase + mrow + quad * 4;
  for (int jt = 0; jt < 4; jt++)
    for (int r = 0; r < 4; r++)
      Y[(size_t)(growb + r) * DINNER + h * DHEAD + jt * 16 + lrow] = f2bf(acc[jt][r]);
}

// ---------------- gated rmsnorm (+ D*X skip) -> bf16 out (vectorized) ----------------
__global__ __launch_bounds__(256) void gatenorm_k(const ushort* __restrict__ Ybf,
                                                  const ushort* __restrict__ zxbf,
                                                  const ushort* __restrict__ xbf,
                                                  const float* __restrict__ Dvec,
                                                  const float* __restrict__ gw,
                                                  ushort* __restrict__ obf) {
  __shared__ float sb[4];
  int r = blockIdx.x;
  int c0 = threadIdx.x * 8;
  const ushort* yr = Ybf + (size_t)r * DINNER;
  const ushort* zr = zxbf + (size_t)r * DINPROJ;
  const ushort* xr = xbf + (size_t)r * CONVDIM;
  ushort* orow = obf + (size_t)r * DINNER;
  shortx8 y8 = *(const shortx8*)(yr + c0);
  shortx8 z8 = *(const shortx8*)(zr + c0);
  shortx8 x8 = *(const shortx8*)(xr + c0);
  float Dv = Dvec[threadIdx.x >> 3];   // 8 cols per thread stay in one head
  float t[8]; float ssq = 0.f;
#pragma unroll
  for (int i = 0; i < 8; i++) {
    float z = bf2f((ushort)z8[i]);
    float yv = bf2f((ushort)y8[i]) + Dv * bf2f((ushort)x8[i]);
    float gv = yv * (z / (1.f + expf(-z)));
    t[i] = gv;
    ssq += gv * gv;
  }
  float s = block_reduce_sum_256(ssq, sb);
  float sc = rsqrtf(s / (float)DINNER + EPSF);
  float4 g0 = *(const float4*)(gw + c0);
  float4 g1 = *(const float4*)(gw + c0 + 4);
  shortx8 o;
  o[0] = (short)f2bf(t[0] * sc * g0.x); o[1] = (short)f2bf(t[1] * sc * g0.y);
  o[2] = (short)f2bf(t[2] * sc * g0.z); o[3] = (short)f2bf(t[3] * sc * g0.w);
  o[4] = (short)f2bf(t[4] * sc * g1.x); o[5] = (short)f2bf(t[5] * sc * g1.y);
  o[6] = (short)f2bf(t[6] * sc * g1.z); o[7] = (short)f2bf(t[7] * sc * g1.w);
  *(shortx8*)(orow + c0) = o;
}

// ---------------- launch ----------------
extern "C" void kernel_launch(void* const* d_in, const int* in_sizes, int n_in,
                              void* d_out, int out_size, void* d_ws, size_t ws_size,
                              hipStream_t stream) {
  const float* x_in     = (const float*)d_in[0];
  const float* in_w     = (const float*)d_in[1];
  const float* conv_w   = (const float*)d_in[2];
  const float* conv_b   = (const float*)d_in[3];
  const float* dt_bias  = (const float*)d_in[4];
  const float* A_log    = (const float*)d_in[5];
  const float* Dvec     = (const float*)d_in[6];
  const float* gnorm_w  = (const float*)d_in[7];
  const float* out_w    = (const float*)d_in[8];
  const float* rms_w    = (const float*)d_in[9];
  float* out = (float*)d_out;

  float* ws = (float*)d_ws;
  size_t o = 0;
  float* x_cur  = ws + o; o += (size_t)MROWS * DMODEL;
  ushort* zx_bf = (ushort*)(ws + o); o += (size_t)MROWS * DINPROJ / 2;
  ushort* xbf   = (ushort*)(ws + o); o += (size_t)MROWS * CONVDIM / 2;
  float* dt_sp  = ws + o; o += (size_t)MROWS * NHEADS;
  float* dtA_cs = ws + o; o += (size_t)BATCH * NCHUNK * NHEADS * CHUNKSZ;
  float* st     = ws + o; o += (size_t)BATCH * NCHUNK * NHEADS * DHEAD * DSTATE;
  ushort* Ybf   = (ushort*)(ws + o); o += (size_t)MROWS * DINNER / 2;
  ushort* act_bf = (ushort*)(ws + o); o += (size_t)MROWS * DINNER / 2;
  size_t base_f = o;

  // hoisted weight area (all 4 layers)
  size_t inw_f  = (size_t)4 * DINPROJ_PAD * DMODEL / 2;  // 8,912,896 floats
  size_t outw_f = (size_t)4 * DMODEL * DINNER / 2;       // 4,194,304 floats
  bool hoist = ws_size >= (base_f + inw_f + outw_f) * sizeof(float);

  ushort* in_bf_all = (ushort*)(ws + base_f);
  ushort* out_bf_all = (ushort*)(ws + base_f + inw_f);
  ushort* w_bf_fb = (ushort*)(ws + base_f);  // fallback: single-layer buffer

  hipMemcpyAsync(x_cur, x_in, (size_t)MROWS * DMODEL * sizeof(float),
                 hipMemcpyDeviceToDevice, stream);

  if (hoist) {
    unsigned ntot = (4u * DINPROJ_PAD * DMODEL + 4u * DMODEL * DINNER) / 8u;
    cvt_w_all<<<(ntot + 255) / 256, 256, 0, stream>>>(in_w, out_w, in_bf_all, out_bf_all);
  }

  for (int i = 0; i < 4; i++) {
    const float* conv_w_i = conv_w  + (size_t)i * CONVDIM * DCONV;
    const float* conv_b_i = conv_b  + (size_t)i * CONVDIM;
    const float* dtb_i    = dt_bias + (size_t)i * NHEADS;
    const float* Alog_i   = A_log   + (size_t)i * NHEADS;
    const float* D_i      = Dvec    + (size_t)i * NHEADS;
    const float* gw_i     = gnorm_w + (size_t)i * DINNER;
    const float* rms_w_i  = rms_w   + (size_t)i * DMODEL;

    const ushort* w1_bf;
    const ushort* w2_bf;
    if (hoist) {
      w1_bf = in_bf_all  + (size_t)i * DINPROJ_PAD * DMODEL;
      w2_bf = out_bf_all + (size_t)i * DMODEL * DINNER;
    } else {
      size_t ns = (size_t)DINPROJ * DMODEL, nd = (size_t)DINPROJ_PAD * DMODEL;
      cvt_bf16_k<<<(nd + 255) / 256, 256, 0, stream>>>(
          in_w + (size_t)i * DINPROJ * DMODEL, w_bf_fb, ns, nd);
      w1_bf = w_bf_fb;
      w2_bf = w_bf_fb;
    }

    rmsnorm_k<<<MROWS, 256, 0, stream>>>(x_cur, rms_w_i, act_bf);
    // GEMM1: grid 34x32 = 1088 blocks; XCD region = 17 x 8 tiles.
    gemm_nt_mfma_pipe<<<(DINPROJ_PAD / 128) * (MROWS / 128), 256, 0, stream>>>(
        act_bf, w1_bf, zx_bf, MROWS, DINPROJ, DMODEL, DINPROJ_PAD / 128, 17, 8);
    convcum_k<<<MROWS / 8 + BATCH * NCHUNK * NHEADS, 256, 0, stream>>>(
        zx_bf, conv_w_i, conv_b_i, xbf, dtb_i, Alog_i, dt_sp, dtA_cs);
    states_mfma<<<BATCH * NCHUNK * NHEADS, 256, 0, stream>>>(xbf, dt_sp, dtA_cs, st);
    scan_k<<<BATCH * NHEADS * 4, 256, 0, stream>>>(st, dtA_cs);
    ydiag_mfma<<<BATCH * NCHUNK * NHEADS * 4, 256, 0, stream>>>(
        xbf, dt_sp, dtA_cs, st, Ybf);
    gatenorm_k<<<MROWS, 256, 0, stream>>>(Ybf, zx_bf, xbf, D_i, gw_i, act_bf);
    if (!hoist) {
      size_t ns = (size_t)DMODEL * DINNER;
      cvt_bf16_k<<<(ns + 255) / 256, 256, 0, stream>>>(
          out_w + (size_t)i * DMODEL * DINNER, (ushort*)w_bf_fb, ns, ns);
    }
    float* outC = (i == 3) ? out : x_cur;
    // GEMM2: 128x64 tiles -> grid 32x16 = 512 blocks = 2 blocks/CU (R7 proven);
    // XCD region = 8 x 8 tiles (nbx=16, ra=2).
    gemm_nt_64<<<(MROWS / 128) * (DMODEL / 64), 256, 0, stream>>>(
        act_bf, w2_bf, outC, x_cur, MROWS, DMODEL, DINNER, DMODEL / 64, 8, 8);
  }
}